// Round 9
// baseline (1355.607 us; speedup 1.0000x reference)
//
#include <hip/hip_runtime.h>
#include <hip/hip_bf16.h>
#include <math.h>

// Problem constants
#define BB    4
#define TT    1024
#define EE    256
#define HIDD  256
#define LLUT  8
#define HGT   384
#define WID   384
#define HWPX  147456      // 384*384
#define GSZ   33
#define G3    35937       // 33^3
#define NCOL  862488      // L*3*G3

// padded intermediate geometry (zero ring -> branch-free 9-tap consumers)
#define PW    386
#define PHW   148996      // 386*386
#define RINGN 1540        // 2*386 + 2*384 border pixels

typedef __attribute__((ext_vector_type(8))) short bf16x8;   // 8 bf16 = 4 VGPRs
typedef __attribute__((ext_vector_type(4))) float f32x4;

// fast gelu (tanh form): max abs dev from exact erf-gelu ~1e-3, threshold 2e-2
__device__ __forceinline__ float gelu_f(float x) {
    float s = 1.5957691216057308f * x * (1.0f + 0.044715f * x * x);
    float e = __expf(s);
    return x - x / (e + 1.0f);   // x*sigmoid(s); safe at +-inf
}

__device__ __forceinline__ ushort f2bf(float x) {
    uint u = __float_as_uint(x);
    return (ushort)((u + 0x7FFFu + ((u >> 16) & 1u)) >> 16);   // RNE
}
__device__ __forceinline__ uint pack2bf(float a, float b) {
    return (uint)f2bf(a) | ((uint)f2bf(b) << 16);
}
__device__ __forceinline__ float bf2f_lo(uint u) { return __uint_as_float(u << 16); }
__device__ __forceinline__ float bf2f_hi(uint u) { return __uint_as_float(u & 0xFFFF0000u); }

__device__ __forceinline__ void unpack32(const uint4* xp, float* xx) {
#pragma unroll
    for (int q = 0; q < 4; ++q) {
        uint4 v = xp[q];
        xx[q * 8 + 0] = bf2f_lo(v.x); xx[q * 8 + 1] = bf2f_hi(v.x);
        xx[q * 8 + 2] = bf2f_lo(v.y); xx[q * 8 + 3] = bf2f_hi(v.y);
        xx[q * 8 + 4] = bf2f_lo(v.z); xx[q * 8 + 5] = bf2f_hi(v.z);
        xx[q * 8 + 6] = bf2f_lo(v.w); xx[q * 8 + 7] = bf2f_hi(v.w);
    }
}

// ---------------------------------------------------------------------------
// K-1: zero the 1-px border ring of act0/act1/act2 (NHWC bf16) and comb
// ([px][8] fp32). Once per launch; producers write interior only.
// grid (7, B, 4 bufs), 256 threads.
// ---------------------------------------------------------------------------
__global__ __launch_bounds__(256) void zero_border_kernel(
    ushort* __restrict__ a0, ushort* __restrict__ a1, ushort* __restrict__ a2,
    float* __restrict__ comb)
{
    const int r = blockIdx.x * 256 + threadIdx.x;
    if (r >= RINGN) return;
    const int b = blockIdx.y;
    const int buf = blockIdx.z;
    int row, col;
    if (r < PW)            { row = 0;      col = r; }
    else if (r < 2 * PW)   { row = PW - 1; col = r - PW; }
    else { int rem = r - 2 * PW; row = 1 + (rem >> 1); col = (rem & 1) ? (PW - 1) : 0; }
    const long px = (long)b * PHW + (long)row * PW + col;
    if (buf < 3) {
        ushort* p = (buf == 0 ? a0 : buf == 1 ? a1 : a2) + px * 32;
        const uint4 z = make_uint4(0u, 0u, 0u, 0u);
        ((uint4*)p)[0] = z; ((uint4*)p)[1] = z; ((uint4*)p)[2] = z; ((uint4*)p)[3] = z;
    } else {
        float4 z4; z4.x = z4.y = z4.z = z4.w = 0.f;
        float* p = comb + px * 8;
        ((float4*)p)[0] = z4; ((float4*)p)[1] = z4;
    }
}

// ---------------------------------------------------------------------------
// K0: embedding-mean partial sums. grid (64, B).
// ---------------------------------------------------------------------------
__global__ __launch_bounds__(256) void emb_partial_kernel(
    const int* __restrict__ tokens, const float* __restrict__ emb,
    float* __restrict__ partial)
{
    const int s = blockIdx.x, b = blockIdx.y, tid = threadIdx.x;
    const int* tok = tokens + b * TT + s * 16;
    float acc = 0.f;
#pragma unroll
    for (int t = 0; t < 16; ++t) acc += emb[tok[t] * EE + tid];
    partial[(b * 64 + s) * EE + tid] = acc;
}

// ---------------------------------------------------------------------------
// K1: fused token head, latency-parallel (r7 version).
// ---------------------------------------------------------------------------
__global__ __launch_bounds__(1024) void mlp_head_kernel(
    const float* __restrict__ partial,
    const float* __restrict__ aw1, const float* __restrict__ ab1,
    const float* __restrict__ aw2, const float* __restrict__ ab2,
    const float* __restrict__ lw1, const float* __restrict__ lb1,
    const float* __restrict__ gw1, const float* __restrict__ gb1,
    const float* __restrict__ gw2, const float* __restrict__ gb2,
    float* __restrict__ h3_out, float* __restrict__ lw_out)
{
    const int b = blockIdx.x;
    const int tid = threadIdx.x;
    const int o = tid & 255;
    const int q = tid >> 8;
    __shared__ float tf[256], h1[256], tf2s[256], h4[64], lg[8];
    __shared__ float red[4][256];

    {
        float acc = 0.f;
#pragma unroll
        for (int s = 0; s < 16; ++s)
            acc += partial[(b * 64 + q * 16 + s) * EE + o];
        red[q][o] = acc;
    }
    __syncthreads();
    if (tid < 256)
        tf[tid] = (red[0][tid] + red[1][tid] + red[2][tid] + red[3][tid]) * (1.0f / TT);
    __syncthreads();

    {
        float s = 0.f;
#pragma unroll 8
        for (int j = 0; j < 64; ++j) {
            const int k = (q << 6) + j;
            s += tf[k] * aw1[k * HIDD + o];
        }
        red[q][o] = s;
    }
    __syncthreads();
    if (tid < 256)
        h1[tid] = gelu_f(red[0][tid] + red[1][tid] + red[2][tid] + red[3][tid] + ab1[tid]);
    __syncthreads();

    {
        float s = 0.f;
#pragma unroll 8
        for (int j = 0; j < 64; ++j) {
            const int k = (q << 6) + j;
            s += h1[k] * aw2[k * HIDD + o];
        }
        red[q][o] = s;
    }
    __syncthreads();
    if (tid < 256)
        tf2s[tid] = red[0][tid] + red[1][tid] + red[2][tid] + red[3][tid] + ab2[tid];
    __syncthreads();

    {
        float s = 0.f;
#pragma unroll 8
        for (int j = 0; j < 64; ++j) {
            const int k = (q << 6) + j;
            s += tf2s[k] * lw1[k * HIDD + o];
        }
        red[q][o] = s;
    }
    __syncthreads();
    if (tid < 256)
        h3_out[b * HIDD + tid] =
            gelu_f(red[0][tid] + red[1][tid] + red[2][tid] + red[3][tid] + lb1[tid]);
    __syncthreads();

    {
        const int o64 = tid & 63, q16 = tid >> 6;
        float s = 0.f;
#pragma unroll
        for (int j = 0; j < 16; ++j) {
            const int k = q16 * 16 + j;
            s += tf2s[k] * gw1[k * 64 + o64];
        }
        ((float*)red)[q16 * 64 + o64] = s;
    }
    __syncthreads();
    if (tid < 64) {
        float s = gb1[tid];
#pragma unroll
        for (int r = 0; r < 16; ++r) s += ((float*)red)[r * 64 + tid];
        h4[tid] = gelu_f(s);
    }
    __syncthreads();

    if (tid < 8) {
        float s = gb2[tid];
#pragma unroll 8
        for (int k = 0; k < 64; ++k) s += h4[k] * gw2[k * LLUT + tid];
        lg[tid] = s;
    }
    __syncthreads();
    if (tid == 0) {
        float m = lg[0];
        for (int i = 1; i < LLUT; ++i) m = fmaxf(m, lg[i]);
        float ssum = 0.f, ex[LLUT];
        for (int i = 0; i < LLUT; ++i) { ex[i] = expf(lg[i] - m); ssum += ex[i]; }
        for (int i = 0; i < LLUT; ++i) lw_out[b * LLUT + i] = ex[i] / ssum;
    }
}

// ---------------------------------------------------------------------------
// K2: big GEMM. Streams 883 MB of w2 once; HBM-bound floor ~140 us.
// ---------------------------------------------------------------------------
__global__ __launch_bounds__(256) void lut_gemm_kernel(
    const float* __restrict__ h3, const float* __restrict__ w2,
    const float* __restrict__ b2, float* __restrict__ lp)
{
    __shared__ float h[BB * HIDD];
    const int tid = threadIdx.x;
    for (int i = tid; i < BB * HIDD; i += 256) h[i] = h3[i];
    __syncthreads();

    const long col = ((long)blockIdx.x * 256 + tid) * 4;
    if (col >= NCOL) return;

    const float4 bias = *(const float4*)(b2 + col);
    float4 a0 = bias, a1 = bias, a2 = bias, a3 = bias;
    const float* wp = w2 + col;
#pragma unroll 4
    for (int k = 0; k < HIDD; ++k) {
        float4 w = *(const float4*)(wp + (long)k * NCOL);
        float h0 = h[k], h1v = h[HIDD + k], h2 = h[2 * HIDD + k], h3v = h[3 * HIDD + k];
        a0.x += h0 * w.x;  a0.y += h0 * w.y;  a0.z += h0 * w.z;  a0.w += h0 * w.w;
        a1.x += h1v * w.x; a1.y += h1v * w.y; a1.z += h1v * w.z; a1.w += h1v * w.w;
        a2.x += h2 * w.x;  a2.y += h2 * w.y;  a2.z += h2 * w.z;  a2.w += h2 * w.w;
        a3.x += h3v * w.x; a3.y += h3v * w.y; a3.z += h3v * w.z; a3.w += h3v * w.w;
    }
    *(float4*)(lp + 0L * NCOL + col) = a0;
    *(float4*)(lp + 1L * NCOL + col) = a1;
    *(float4*)(lp + 2L * NCOL + col) = a2;
    *(float4*)(lp + 3L * NCOL + col) = a3;
}

// ---------------------------------------------------------------------------
// K3: combine 8 LUTs with softmax weights -> one 3-channel LUT per batch.
// ---------------------------------------------------------------------------
__global__ __launch_bounds__(256) void combine_kernel(
    const float* __restrict__ lp, const float* __restrict__ lwv,
    float* __restrict__ clut)
{
    const int v = blockIdx.x * 256 + threadIdx.x;
    const int b = blockIdx.y;
    if (v >= G3) return;
    float w[LLUT];
#pragma unroll
    for (int l = 0; l < LLUT; ++l) w[l] = lwv[b * LLUT + l];
#pragma unroll
    for (int c = 0; c < 3; ++c) {
        float s = 0.f;
#pragma unroll
        for (int l = 0; l < LLUT; ++l)
            s += w[l] * lp[(long)b * NCOL + (long)(l * 3 + c) * G3 + v];
        clut[(long)(b * 3 + c) * G3 + v] = s;
    }
}

// ---------------------------------------------------------------------------
// K4+K7 merged, v2: 2 px/thread, branch-free. Trilinear LUT apply (comb slots
// 0..2) + 32->3 proc conv from padded act2 (slots 4..6) -> padded comb.
// ---------------------------------------------------------------------------
__global__ __launch_bounds__(256) void applylut_out3_kernel(
    const float* __restrict__ clut, const float* __restrict__ recon,
    const ushort* __restrict__ act2, const float* __restrict__ wgt,
    const float* __restrict__ bias, float* __restrict__ comb)
{
    const int p0 = (blockIdx.x * 256 + threadIdx.x) * 2;
    const int b = blockIdx.y;
    const int hh = p0 / WID, ww = p0 - hh * WID;

    // --- LUT part (2 px) ---
    float lut_out[2][3];
    const float* rc = recon + (long)b * 3 * HWPX;
    const float2 rr = *(const float2*)(rc + p0);
    const float2 rg = *(const float2*)(rc + HWPX + p0);
    const float2 rb = *(const float2*)(rc + 2 * HWPX + p0);
#pragma unroll
    for (int px = 0; px < 2; ++px) {
        float cr = fminf(fmaxf((px ? rr.y : rr.x) * 32.f, 0.f), 32.f);
        float cg = fminf(fmaxf((px ? rg.y : rg.x) * 32.f, 0.f), 32.f);
        float cb = fminf(fmaxf((px ? rb.y : rb.x) * 32.f, 0.f), 32.f);
        float fr = fminf(floorf(cr), 31.f);
        float fg = fminf(floorf(cg), 31.f);
        float fb = fminf(floorf(cb), 31.f);
        float tr = cr - fr, tg = cg - fg, tb_ = cb - fb;
        int idx = (((int)fr * GSZ + (int)fg) * GSZ + (int)fb);
#pragma unroll
        for (int ch = 0; ch < 3; ++ch) {
            const float* lut = clut + (long)(b * 3 + ch) * G3;
            float v000 = lut[idx],                   v001 = lut[idx + 1];
            float v010 = lut[idx + GSZ],             v011 = lut[idx + GSZ + 1];
            float v100 = lut[idx + GSZ * GSZ],       v101 = lut[idx + GSZ * GSZ + 1];
            float v110 = lut[idx + GSZ * GSZ + GSZ], v111 = lut[idx + GSZ * GSZ + GSZ + 1];
            float c00 = v000 + (v001 - v000) * tb_;
            float c01 = v010 + (v011 - v010) * tb_;
            float c10 = v100 + (v101 - v100) * tb_;
            float c11 = v110 + (v111 - v110) * tb_;
            float c0 = c00 + (c01 - c00) * tg;
            float c1 = c10 + (c11 - c10) * tg;
            lut_out[px][ch] = c0 + (c1 - c0) * tr;
        }
    }

    // --- proc 32->3 conv part: padded act2, branch-free, shared cols ---
    float a0[3] = {bias[0], bias[1], bias[2]};
    float a1[3] = {bias[0], bias[1], bias[2]};
#pragma unroll
    for (int dh = 0; dh < 3; ++dh) {
        const ushort* rp = act2 + ((long)b * PHW + (long)(hh + dh) * PW + ww) * 32;
#pragma unroll
        for (int c = 0; c < 4; ++c) {
            float xx[32];
            unpack32((const uint4*)(rp + c * 32), xx);
            if (c < 3) {
                const int tap = dh * 3 + c;
#pragma unroll
                for (int o = 0; o < 3; ++o)
#pragma unroll
                    for (int ci = 0; ci < 32; ++ci)
                        a0[o] += xx[ci] * wgt[o * 288 + ci * 9 + tap];
            }
            if (c > 0) {
                const int tap = dh * 3 + c - 1;
#pragma unroll
                for (int o = 0; o < 3; ++o)
#pragma unroll
                    for (int ci = 0; ci < 32; ++ci)
                        a1[o] += xx[ci] * wgt[o * 288 + ci * 9 + tap];
            }
        }
    }

    float* cb = comb + ((long)b * PHW + (long)(hh + 1) * PW + (ww + 1)) * 8;
    float4 r4;
    r4.x = lut_out[0][0]; r4.y = lut_out[0][1]; r4.z = lut_out[0][2]; r4.w = 0.f;
    *(float4*)(cb + 0) = r4;
    r4.x = a0[0]; r4.y = a0[1]; r4.z = a0[2]; r4.w = 0.f;
    *(float4*)(cb + 4) = r4;
    r4.x = lut_out[1][0]; r4.y = lut_out[1][1]; r4.z = lut_out[1][2]; r4.w = 0.f;
    *(float4*)(cb + 8) = r4;
    r4.x = a1[0]; r4.y = a1[1]; r4.z = a1[2]; r4.w = 0.f;
    *(float4*)(cb + 12) = r4;
}

// ---------------------------------------------------------------------------
// K5: 3->32 conv (img fp32 NCHW -> padded act NHWC bf16), gelu. 2 px/thread.
// ---------------------------------------------------------------------------
__global__ __launch_bounds__(256) void conv_in3_kernel(
    const float* __restrict__ img, const float* __restrict__ wgt,
    const float* __restrict__ bias, ushort* __restrict__ out)
{
    const int tid = threadIdx.x;
    const int p0 = (blockIdx.x * 256 + tid) * 2;
    const int b = blockIdx.y;
    const int hh = p0 / WID, ww = p0 - hh * WID;

    float acc[32][2];
#pragma unroll
    for (int o = 0; o < 32; ++o) { float bv = bias[o]; acc[o][0] = bv; acc[o][1] = bv; }

    const bool wlo = (ww > 0), whi = (ww + 2 < WID);
#pragma unroll
    for (int ci = 0; ci < 3; ++ci) {
        const float* ip = img + (long)(b * 3 + ci) * HWPX;
        float x[3][4];
#pragma unroll
        for (int dh = 0; dh < 3; ++dh) {
            const int hs = hh + dh - 1;
            const bool hok = (hs >= 0) && (hs < HGT);
            const float* rp_ = ip + hs * WID + ww;
            x[dh][0] = (hok && wlo) ? rp_[-1] : 0.f;
            x[dh][1] = hok ? rp_[0] : 0.f;
            x[dh][2] = hok ? rp_[1] : 0.f;
            x[dh][3] = (hok && whi) ? rp_[2] : 0.f;
        }
#pragma unroll
        for (int o = 0; o < 32; ++o) {
            const float* wv = wgt + o * 27 + ci * 9;   // uniform -> s_load
#pragma unroll
            for (int dh = 0; dh < 3; ++dh)
#pragma unroll
                for (int dw = 0; dw < 3; ++dw) {
                    const float w = wv[dh * 3 + dw];
                    acc[o][0] += x[dh][dw]     * w;
                    acc[o][1] += x[dh][dw + 1] * w;
                }
        }
    }

    ushort* op = out + ((long)b * PHW + (long)(hh + 1) * PW + (ww + 1)) * 32;
#pragma unroll
    for (int px = 0; px < 2; ++px) {
        uint u[16];
#pragma unroll
        for (int o2 = 0; o2 < 16; ++o2)
            u[o2] = pack2bf(gelu_f(acc[2 * o2][px]), gelu_f(acc[2 * o2 + 1][px]));
        uint4* dst = (uint4*)(op + px * 32);
#pragma unroll
        for (int q = 0; q < 4; ++q)
            dst[q] = make_uint4(u[4 * q], u[4 * q + 1], u[4 * q + 2], u[4 * q + 3]);
    }
}

// ---------------------------------------------------------------------------
// K6: MFMA 32->32 conv, staged LDS halo, padded IO (guard-free staging).
// Tile 8 rows x 64 px, 8 waves. Halo 10x66, CSTR=40 pad. 71.3 KB -> 2 blk/CU.
// ---------------------------------------------------------------------------
#define TH2 8
#define TW2 64
#define HALO_H2 10
#define HALO_W2 66
#define CSTR 40   // padded ushort stride per pixel (80 B)

template <bool HAS_RES>
__global__ __launch_bounds__(512, 4) void conv32_mfma(
    const ushort* __restrict__ in, const ushort* __restrict__ res,
    const float* __restrict__ wgt, const float* __restrict__ bias,
    const float* __restrict__ bn_g, const float* __restrict__ bn_bt,
    ushort* __restrict__ out)
{
    __shared__ ushort halo[HALO_H2 * HALO_W2 * CSTR];   // 52800 B
    __shared__ ushort wlA[9 * 2 * 64 * 8];              // 18432 B, lane-linear
    __shared__ float s_scale[32], s_shift[32];

    const int tid = threadIdx.x;
    const int b  = blockIdx.z;
    const int h0 = blockIdx.y * TH2;
    const int w0 = blockIdx.x * TW2;

    // pack A-frags: wlA[((tap*2+half)*64 + lane)*8 + j]
    for (int i = tid; i < 9 * 2 * 64 * 8; i += 512) {
        const int j    = i & 7;
        const int lane_= (i >> 3) & 63;
        const int half = (i >> 9) & 1;
        const int tap  = i >> 10;
        const int co = half * 16 + (lane_ & 15);
        const int ci = (lane_ >> 4) * 8 + j;
        wlA[i] = f2bf(wgt[co * 288 + ci * 9 + tap]);
    }
    if (tid < 32) {
        float sg = bn_g[tid] * 0.9999950000375f;   // g*(1+1e-5)^-0.5
        s_scale[tid] = sg;
        s_shift[tid] = bias[tid] * sg + bn_bt[tid];
    }

    // stage halo from PADDED input: no guards at all
    const ushort* inb = in + (long)b * PHW * 32;
    for (int i = tid; i < HALO_H2 * HALO_W2 * 4; i += 512) {
        const int row = i / (HALO_W2 * 4);
        const int rem = i - row * (HALO_W2 * 4);
        const int px = rem >> 2, q = rem & 3;
        uint4 v = *(const uint4*)(inb + ((long)(h0 + row) * PW + (w0 + px)) * 32 + q * 8);
        *(uint4*)(&halo[(row * HALO_W2 + px) * CSTR + q * 8]) = v;
    }
    __syncthreads();

    const int lane = tid & 63, wid = tid >> 6;
    const int l15 = lane & 15, kg = lane >> 4;
    const int r = wid;                      // one output row per wave

    f32x4 acc[4][2];
#pragma unroll
    for (int f = 0; f < 4; ++f)
#pragma unroll
        for (int cf = 0; cf < 2; ++cf)
            acc[f][cf] = (f32x4){0.f, 0.f, 0.f, 0.f};

#pragma unroll
    for (int tap = 0; tap < 9; ++tap) {
        const int dh = tap / 3, dw = tap - dh * 3;
        const bf16x8 a0 = *(const bf16x8*)(&wlA[((tap * 2 + 0) * 64 + lane) * 8]);
        const bf16x8 a1 = *(const bf16x8*)(&wlA[((tap * 2 + 1) * 64 + lane) * 8]);
#pragma unroll
        for (int f = 0; f < 4; ++f) {
            const int c0 = f * 16;
            const bf16x8 bfv = *(const bf16x8*)(
                &halo[((r + dh) * HALO_W2 + (c0 + dw + l15)) * CSTR + kg * 8]);
            acc[f][0] = __builtin_amdgcn_mfma_f32_16x16x32_bf16(a0, bfv, acc[f][0], 0, 0, 0);
            acc[f][1] = __builtin_amdgcn_mfma_f32_16x16x32_bf16(a1, bfv, acc[f][1], 0, 0, 0);
        }
    }

    // epilogue: scale/shift (+res) + gelu -> padded bf16 NHWC
#pragma unroll
    for (int f = 0; f < 4; ++f) {
        const int c0 = f * 16;
        const long gpx = (long)b * PHW + (long)(h0 + r + 1) * PW + (w0 + c0 + l15 + 1);
#pragma unroll
        for (int cf = 0; cf < 2; ++cf) {
            const int co0 = cf * 16 + kg * 4;
            const float4 sc = *(const float4*)(&s_scale[co0]);
            const float4 sh = *(const float4*)(&s_shift[co0]);
            float v0 = acc[f][cf][0] * sc.x + sh.x;
            float v1 = acc[f][cf][1] * sc.y + sh.y;
            float v2 = acc[f][cf][2] * sc.z + sh.z;
            float v3 = acc[f][cf][3] * sc.w + sh.w;
            if (HAS_RES) {
                const uint2 rv = *(const uint2*)(res + gpx * 32 + co0);
                v0 += bf2f_lo(rv.x); v1 += bf2f_hi(rv.x);
                v2 += bf2f_lo(rv.y); v3 += bf2f_hi(rv.y);
            }
            uint2 o;
            o.x = pack2bf(gelu_f(v0), gelu_f(v1));
            o.y = pack2bf(gelu_f(v2), gelu_f(v3));
            *(uint2*)(out + gpx * 32 + co0) = o;
        }
    }
}

// ---------------------------------------------------------------------------
// K8 v2: 6->32 conv (padded comb fp32 [px][8] -> padded act NHWC bf16), gelu.
// 2 px/thread, branch-free, shared cols.
// ---------------------------------------------------------------------------
__global__ __launch_bounds__(256) void conv_in6_kernel(
    const float* __restrict__ comb, const float* __restrict__ wgt,
    const float* __restrict__ bias, ushort* __restrict__ out)
{
    const int p0 = (blockIdx.x * 256 + threadIdx.x) * 2;
    const int b = blockIdx.y;
    const int hh = p0 / WID, ww = p0 - hh * WID;

    float a0[32], a1[32];
#pragma unroll
    for (int o = 0; o < 32; ++o) { float bv = bias[o]; a0[o] = bv; a1[o] = bv; }

#pragma unroll
    for (int dh = 0; dh < 3; ++dh) {
        const float* cp = comb + ((long)b * PHW + (long)(hh + dh) * PW + ww) * 8;
#pragma unroll
        for (int c = 0; c < 4; ++c) {
            const float4 qa = *(const float4*)(cp + c * 8);
            const float4 qb = *(const float4*)(cp + c * 8 + 4);
            const float xs[6] = {qa.x, qa.y, qa.z, qb.x, qb.y, qb.z};
            if (c < 3) {
                const int tap = dh * 3 + c;
#pragma unroll
                for (int o = 0; o < 32; ++o) {
                    const float* wv = wgt + o * 54 + tap;   // uniform -> s_load
                    a0[o] += xs[0] * wv[0]  + xs[1] * wv[9]  + xs[2] * wv[18]
                           + xs[3] * wv[27] + xs[4] * wv[36] + xs[5] * wv[45];
                }
            }
            if (c > 0) {
                const int tap = dh * 3 + c - 1;
#pragma unroll
                for (int o = 0; o < 32; ++o) {
                    const float* wv = wgt + o * 54 + tap;
                    a1[o] += xs[0] * wv[0]  + xs[1] * wv[9]  + xs[2] * wv[18]
                           + xs[3] * wv[27] + xs[4] * wv[36] + xs[5] * wv[45];
                }
            }
        }
    }

    ushort* op = out + ((long)b * PHW + (long)(hh + 1) * PW + (ww + 1)) * 32;
    {
        uint u[16];
#pragma unroll
        for (int o2 = 0; o2 < 16; ++o2)
            u[o2] = pack2bf(gelu_f(a0[2 * o2]), gelu_f(a0[2 * o2 + 1]));
        uint4* dst = (uint4*)op;
#pragma unroll
        for (int q = 0; q < 4; ++q)
            dst[q] = make_uint4(u[4 * q], u[4 * q + 1], u[4 * q + 2], u[4 * q + 3]);
    }
    {
        uint u[16];
#pragma unroll
        for (int o2 = 0; o2 < 16; ++o2)
            u[o2] = pack2bf(gelu_f(a1[2 * o2]), gelu_f(a1[2 * o2 + 1]));
        uint4* dst = (uint4*)(op + 32);
#pragma unroll
        for (int q = 0; q < 4; ++q)
            dst[q] = make_uint4(u[4 * q], u[4 * q + 1], u[4 * q + 2], u[4 * q + 3]);
    }
}

// ---------------------------------------------------------------------------
// K9 v2: final 32->3 conv (padded NHWC bf16) + img -> d_out fp32 NCHW.
// 2 px/thread, branch-free, shared cols.
// ---------------------------------------------------------------------------
__global__ __launch_bounds__(256) void conv_final_kernel(
    const ushort* __restrict__ in, const float* __restrict__ wgt,
    const float* __restrict__ bias, const float* __restrict__ img,
    float* __restrict__ outp)
{
    const int p0 = (blockIdx.x * 256 + threadIdx.x) * 2;
    const int b = blockIdx.y;
    const int hh = p0 / WID, ww = p0 - hh * WID;

    float a0[3] = {bias[0], bias[1], bias[2]};
    float a1[3] = {bias[0], bias[1], bias[2]};

#pragma unroll
    for (int dh = 0; dh < 3; ++dh) {
        const ushort* rp = in + ((long)b * PHW + (long)(hh + dh) * PW + ww) * 32;
#pragma unroll
        for (int c = 0; c < 4; ++c) {
            float xx[32];
            unpack32((const uint4*)(rp + c * 32), xx);
            if (c < 3) {
                const int tap = dh * 3 + c;
#pragma unroll
                for (int o = 0; o < 3; ++o)
#pragma unroll
                    for (int ci = 0; ci < 32; ++ci)
                        a0[o] += xx[ci] * wgt[o * 288 + ci * 9 + tap];
            }
            if (c > 0) {
                const int tap = dh * 3 + c - 1;
#pragma unroll
                for (int o = 0; o < 3; ++o)
#pragma unroll
                    for (int ci = 0; ci < 32; ++ci)
                        a1[o] += xx[ci] * wgt[o * 288 + ci * 9 + tap];
            }
        }
    }
#pragma unroll
    for (int o = 0; o < 3; ++o) {
        const float2 iv = *(const float2*)(img + (long)(b * 3 + o) * HWPX + p0);
        float2 ov; ov.x = a0[o] + iv.x; ov.y = a1[o] + iv.y;
        *(float2*)(outp + (long)(b * 3 + o) * HWPX + p0) = ov;
    }
}

// ---------------------------------------------------------------------------
extern "C" void kernel_launch(void* const* d_in, const int* in_sizes, int n_in,
                              void* d_out, int out_size, void* d_ws, size_t ws_size,
                              hipStream_t stream)
{
    const int*   tokens  = (const int*)d_in[0];
    const float* img     = (const float*)d_in[1];
    const float* recon   = (const float*)d_in[2];
    const float* emb     = (const float*)d_in[3];
    const float* agg_w1  = (const float*)d_in[4];
    const float* agg_b1  = (const float*)d_in[5];
    const float* agg_w2  = (const float*)d_in[6];
    const float* agg_b2  = (const float*)d_in[7];
    const float* lut_w1  = (const float*)d_in[8];
    const float* lut_b1  = (const float*)d_in[9];
    const float* lut_w2  = (const float*)d_in[10];
    const float* lut_b2  = (const float*)d_in[11];
    const float* wg_w1   = (const float*)d_in[12];
    const float* wg_b1   = (const float*)d_in[13];
    const float* wg_w2   = (const float*)d_in[14];
    const float* wg_b2   = (const float*)d_in[15];
    const float* rp_cin_w = (const float*)d_in[16];
    const float* rp_cin_b = (const float*)d_in[17];
    const float* rp_rbA_w = (const float*)d_in[18];
    const float* rp_rbA_b = (const float*)d_in[19];
    const float* rp_rbA_g = (const float*)d_in[20];
    const float* rp_rbA_bt= (const float*)d_in[21];
    const float* rp_rbB_w = (const float*)d_in[22];
    const float* rp_rbB_b = (const float*)d_in[23];
    const float* rp_rbB_g = (const float*)d_in[24];
    const float* rp_rbB_bt= (const float*)d_in[25];
    const float* rp_cout_w= (const float*)d_in[26];
    const float* rp_cout_b= (const float*)d_in[27];
    const float* fu_cin_w = (const float*)d_in[28];
    const float* fu_cin_b = (const float*)d_in[29];
    const float* fu_rbA_w = (const float*)d_in[30];
    const float* fu_rbA_b = (const float*)d_in[31];
    const float* fu_rbA_g = (const float*)d_in[32];
    const float* fu_rbA_bt= (const float*)d_in[33];
    const float* fu_rbB_w = (const float*)d_in[34];
    const float* fu_rbB_b = (const float*)d_in[35];
    const float* fu_rbB_g = (const float*)d_in[36];
    const float* fu_rbB_bt= (const float*)d_in[37];
    const float* fu_cout_w= (const float*)d_in[38];
    const float* fu_cout_b= (const float*)d_in[39];

    float* ws = (float*)d_ws;
    float*  h3      = ws;                       // 1024
    float*  lwv     = ws + 1024;                // 32
    float*  partial = ws + 2048;                // 65536
    float*  lp      = ws + 69632;               // 3449952
    float*  clut    = ws + 3519584;             // 431244
    float*  comb    = ws + 3952640;             // 4*PHW*8 = 4767872 fp32 (padded)
    ushort* act0    = (ushort*)(ws + 8720512);  // 4*PHW*32 ushorts (padded)
    ushort* act1    = (ushort*)(ws + 18256256);
    ushort* act2    = (ushort*)(ws + 27792000);
    float*  outp    = (float*)d_out;

    // zero border rings once (producers write interior only)
    zero_border_kernel<<<dim3(7, BB, 4), dim3(256), 0, stream>>>(act0, act1, act2, comb);

    // token head
    emb_partial_kernel<<<dim3(64, BB), dim3(256), 0, stream>>>(tokens, emb, partial);
    mlp_head_kernel<<<dim3(BB), dim3(1024), 0, stream>>>(
        partial, agg_w1, agg_b1, agg_w2, agg_b2,
        lut_w1, lut_b1, wg_w1, wg_b1, wg_w2, wg_b2, h3, lwv);

    // LUT path
    lut_gemm_kernel<<<dim3((NCOL / 4 + 255) / 256), dim3(256), 0, stream>>>(
        h3, lut_w2, lut_b2, lp);
    combine_kernel<<<dim3((G3 + 255) / 256, BB), dim3(256), 0, stream>>>(lp, lwv, clut);

    const dim3 g2(HWPX / 512, BB), blk(256);
    const dim3 gm(WID / TW2, HGT / TH2, BB), bm(512);

    // proc branch: img -> act0 -> act1 -> act2
    conv_in3_kernel<<<g2, blk, 0, stream>>>(img, rp_cin_w, rp_cin_b, act0);
    conv32_mfma<false><<<gm, bm, 0, stream>>>(
        act0, nullptr, rp_rbA_w, rp_rbA_b, rp_rbA_g, rp_rbA_bt, act1);
    conv32_mfma<true><<<gm, bm, 0, stream>>>(
        act1, act0, rp_rbB_w, rp_rbB_b, rp_rbB_g, rp_rbB_bt, act2);

    // merged: LUT apply + proc 32->3 -> comb (padded)
    applylut_out3_kernel<<<g2, blk, 0, stream>>>(
        clut, recon, act2, rp_cout_w, rp_cout_b, comb);

    // fuse branch: comb -> act0 -> act1 -> act2 -> d_out (+img)
    conv_in6_kernel<<<g2, blk, 0, stream>>>(comb, fu_cin_w, fu_cin_b, act0);
    conv32_mfma<false><<<gm, bm, 0, stream>>>(
        act0, nullptr, fu_rbA_w, fu_rbA_b, fu_rbA_g, fu_rbA_bt, act1);
    conv32_mfma<true><<<gm, bm, 0, stream>>>(
        act1, act0, fu_rbB_w, fu_rbB_b, fu_rbB_g, fu_rbB_bt, act2);
    conv_final_kernel<<<g2, blk, 0, stream>>>(act2, fu_cout_w, fu_cout_b, img, outp);
}

// Round 13
// 564.328 us; speedup vs baseline: 2.4022x; 2.4022x over previous
//
#include <hip/hip_runtime.h>
#include <hip/hip_bf16.h>
#include <math.h>

// Problem constants
#define BB    4
#define TT    1024
#define EE    256
#define HIDD  256
#define LLUT  8
#define HGT   384
#define WID   384
#define HWPX  147456      // 384*384
#define GSZ   33
#define G3    35937       // 33^3
#define NCOL  862488      // L*3*G3

typedef __attribute__((ext_vector_type(8))) short bf16x8;   // 8 bf16 = 4 VGPRs
typedef __attribute__((ext_vector_type(4))) float f32x4;

// fast gelu (tanh form): max abs dev from exact erf-gelu ~1e-3, threshold 2e-2
__device__ __forceinline__ float gelu_f(float x) {
    float s = 1.5957691216057308f * x * (1.0f + 0.044715f * x * x);
    float e = __expf(s);
    return x - x / (e + 1.0f);   // x*sigmoid(s); safe at +-inf
}

__device__ __forceinline__ ushort f2bf(float x) {
    uint u = __float_as_uint(x);
    return (ushort)((u + 0x7FFFu + ((u >> 16) & 1u)) >> 16);   // RNE
}
__device__ __forceinline__ uint pack2bf(float a, float b) {
    return (uint)f2bf(a) | ((uint)f2bf(b) << 16);
}
__device__ __forceinline__ float bf2f_lo(uint u) { return __uint_as_float(u << 16); }
__device__ __forceinline__ float bf2f_hi(uint u) { return __uint_as_float(u & 0xFFFF0000u); }

// ---------------------------------------------------------------------------
// K0: embedding-mean partial sums. grid (64, B).
// ---------------------------------------------------------------------------
__global__ __launch_bounds__(256) void emb_partial_kernel(
    const int* __restrict__ tokens, const float* __restrict__ emb,
    float* __restrict__ partial)
{
    const int s = blockIdx.x, b = blockIdx.y, tid = threadIdx.x;
    const int* tok = tokens + b * TT + s * 16;
    float acc = 0.f;
#pragma unroll
    for (int t = 0; t < 16; ++t) acc += emb[tok[t] * EE + tid];
    partial[(b * 64 + s) * EE + tid] = acc;
}

// ---------------------------------------------------------------------------
// K1: fused token head, latency-parallel (r7 version, measured-good).
// ---------------------------------------------------------------------------
__global__ __launch_bounds__(1024) void mlp_head_kernel(
    const float* __restrict__ partial,
    const float* __restrict__ aw1, const float* __restrict__ ab1,
    const float* __restrict__ aw2, const float* __restrict__ ab2,
    const float* __restrict__ lw1, const float* __restrict__ lb1,
    const float* __restrict__ gw1, const float* __restrict__ gb1,
    const float* __restrict__ gw2, const float* __restrict__ gb2,
    float* __restrict__ h3_out, float* __restrict__ lw_out)
{
    const int b = blockIdx.x;
    const int tid = threadIdx.x;
    const int o = tid & 255;
    const int q = tid >> 8;
    __shared__ float tf[256], h1[256], tf2s[256], h4[64], lg[8];
    __shared__ float red[4][256];

    {
        float acc = 0.f;
#pragma unroll
        for (int s = 0; s < 16; ++s)
            acc += partial[(b * 64 + q * 16 + s) * EE + o];
        red[q][o] = acc;
    }
    __syncthreads();
    if (tid < 256)
        tf[tid] = (red[0][tid] + red[1][tid] + red[2][tid] + red[3][tid]) * (1.0f / TT);
    __syncthreads();

    {
        float s = 0.f;
#pragma unroll 8
        for (int j = 0; j < 64; ++j) {
            const int k = (q << 6) + j;
            s += tf[k] * aw1[k * HIDD + o];
        }
        red[q][o] = s;
    }
    __syncthreads();
    if (tid < 256)
        h1[tid] = gelu_f(red[0][tid] + red[1][tid] + red[2][tid] + red[3][tid] + ab1[tid]);
    __syncthreads();

    {
        float s = 0.f;
#pragma unroll 8
        for (int j = 0; j < 64; ++j) {
            const int k = (q << 6) + j;
            s += h1[k] * aw2[k * HIDD + o];
        }
        red[q][o] = s;
    }
    __syncthreads();
    if (tid < 256)
        tf2s[tid] = red[0][tid] + red[1][tid] + red[2][tid] + red[3][tid] + ab2[tid];
    __syncthreads();

    {
        float s = 0.f;
#pragma unroll 8
        for (int j = 0; j < 64; ++j) {
            const int k = (q << 6) + j;
            s += tf2s[k] * lw1[k * HIDD + o];
        }
        red[q][o] = s;
    }
    __syncthreads();
    if (tid < 256)
        h3_out[b * HIDD + tid] =
            gelu_f(red[0][tid] + red[1][tid] + red[2][tid] + red[3][tid] + lb1[tid]);
    __syncthreads();

    {
        const int o64 = tid & 63, q16 = tid >> 6;
        float s = 0.f;
#pragma unroll
        for (int j = 0; j < 16; ++j) {
            const int k = q16 * 16 + j;
            s += tf2s[k] * gw1[k * 64 + o64];
        }
        ((float*)red)[q16 * 64 + o64] = s;
    }
    __syncthreads();
    if (tid < 64) {
        float s = gb1[tid];
#pragma unroll
        for (int r = 0; r < 16; ++r) s += ((float*)red)[r * 64 + tid];
        h4[tid] = gelu_f(s);
    }
    __syncthreads();

    if (tid < 8) {
        float s = gb2[tid];
#pragma unroll 8
        for (int k = 0; k < 64; ++k) s += h4[k] * gw2[k * LLUT + tid];
        lg[tid] = s;
    }
    __syncthreads();
    if (tid == 0) {
        float m = lg[0];
        for (int i = 1; i < LLUT; ++i) m = fmaxf(m, lg[i]);
        float ssum = 0.f, ex[LLUT];
        for (int i = 0; i < LLUT; ++i) { ex[i] = expf(lg[i] - m); ssum += ex[i]; }
        for (int i = 0; i < LLUT; ++i) lw_out[b * LLUT + i] = ex[i] / ssum;
    }
}

// ---------------------------------------------------------------------------
// K2 v2: fused LUT-GEMM + softmax-combine -> clut directly (no lp buffer).
// Thread owns one (c, v) output; accumulates acc[b][l] over k for the 8
// l-column-streams, then applies lw. w2 still read exactly once (883 MB,
// coalesced 256B/wave segments per stream). Saves 27.6 MB lp traffic + one
// kernel + one launch gap vs the separate combine.
// grid: ceil(3*G3/256) = 422 blocks.
// ---------------------------------------------------------------------------
__global__ __launch_bounds__(256) void lut_fused_kernel(
    const float* __restrict__ h3, const float* __restrict__ lwv,
    const float* __restrict__ w2, const float* __restrict__ b2,
    float* __restrict__ clut)
{
    __shared__ float h[BB * HIDD];
    __shared__ float lws[BB * LLUT];
    const int tid = threadIdx.x;
    for (int i = tid; i < BB * HIDD; i += 256) h[i] = h3[i];
    if (tid < BB * LLUT) lws[tid] = lwv[tid];
    __syncthreads();

    const int idx = blockIdx.x * 256 + tid;
    if (idx >= 3 * G3) return;
    const int c = idx / G3, v = idx - c * G3;

    float acc[BB][LLUT];
#pragma unroll
    for (int b = 0; b < BB; ++b)
#pragma unroll
        for (int l = 0; l < LLUT; ++l) acc[b][l] = 0.f;

    const float* wbase = w2 + (long)c * G3 + v;   // + l*3*G3 + k*NCOL
#pragma unroll 4
    for (int k = 0; k < HIDD; ++k) {
        const float* row = wbase + (long)k * NCOL;
        float wl[LLUT];
#pragma unroll
        for (int l = 0; l < LLUT; ++l) wl[l] = row[l * 3 * G3];
#pragma unroll
        for (int b = 0; b < BB; ++b) {
            const float hb = h[b * HIDD + k];
#pragma unroll
            for (int l = 0; l < LLUT; ++l) acc[b][l] += wl[l] * hb;
        }
    }

    float bb[LLUT];
#pragma unroll
    for (int l = 0; l < LLUT; ++l) bb[l] = b2[(long)(l * 3 + c) * G3 + v];

#pragma unroll
    for (int b = 0; b < BB; ++b) {
        float s = 0.f;
#pragma unroll
        for (int l = 0; l < LLUT; ++l) s += lws[b * LLUT + l] * (acc[b][l] + bb[l]);
        clut[(long)(b * 3 + c) * G3 + v] = s;
    }
}

// ---------------------------------------------------------------------------
// K4+K7 merged (r7 version): trilinear LUT apply (comb slots 0..2) + 32->3
// proc conv from act2 (slots 4..6) -> comb [px][8] fp32.
// ---------------------------------------------------------------------------
__global__ __launch_bounds__(256) void applylut_out3_kernel(
    const float* __restrict__ clut, const float* __restrict__ recon,
    const ushort* __restrict__ act2, const float* __restrict__ wgt,
    const float* __restrict__ bias, float* __restrict__ comb)
{
    const int p = blockIdx.x * 256 + threadIdx.x;
    const int b = blockIdx.y;

    // --- LUT part ---
    const float* rc = recon + (long)b * 3 * HWPX;
    float cr = fminf(fmaxf(rc[p] * 32.f, 0.f), 32.f);
    float cg = fminf(fmaxf(rc[HWPX + p] * 32.f, 0.f), 32.f);
    float cb = fminf(fmaxf(rc[2 * HWPX + p] * 32.f, 0.f), 32.f);
    float fr = fminf(floorf(cr), 31.f);
    float fg = fminf(floorf(cg), 31.f);
    float fb = fminf(floorf(cb), 31.f);
    float tr = cr - fr, tg = cg - fg, tb_ = cb - fb;
    int idx = (((int)fr * GSZ + (int)fg) * GSZ + (int)fb);
    float c[3];
#pragma unroll
    for (int ch = 0; ch < 3; ++ch) {
        const float* lut = clut + (long)(b * 3 + ch) * G3;
        float v000 = lut[idx],                  v001 = lut[idx + 1];
        float v010 = lut[idx + GSZ],            v011 = lut[idx + GSZ + 1];
        float v100 = lut[idx + GSZ * GSZ],      v101 = lut[idx + GSZ * GSZ + 1];
        float v110 = lut[idx + GSZ * GSZ + GSZ], v111 = lut[idx + GSZ * GSZ + GSZ + 1];
        float c00 = v000 + (v001 - v000) * tb_;
        float c01 = v010 + (v011 - v010) * tb_;
        float c10 = v100 + (v101 - v100) * tb_;
        float c11 = v110 + (v111 - v110) * tb_;
        float c0 = c00 + (c01 - c00) * tg;
        float c1 = c10 + (c11 - c10) * tg;
        c[ch] = c0 + (c1 - c0) * tr;
    }
    float4 r4; r4.x = c[0]; r4.y = c[1]; r4.z = c[2]; r4.w = 0.f;
    *(float4*)(comb + ((long)b * HWPX + p) * 8) = r4;

    // --- proc 32->3 conv part ---
    const int hh = p / WID, ww = p - hh * WID;
    float acc[3] = {bias[0], bias[1], bias[2]};
#pragma unroll
    for (int tap = 0; tap < 9; ++tap) {
        const int dh = tap / 3, dw = tap - dh * 3;
        const int gh = hh + dh - 1, gw = ww + dw - 1;
        if (gh < 0 || gh >= HGT || gw < 0 || gw >= WID) continue;
        const uint4* xp = (const uint4*)(act2 + ((long)b * HWPX + gh * WID + gw) * 32);
        float xx[32];
#pragma unroll
        for (int q = 0; q < 4; ++q) {
            uint4 v = xp[q];
            xx[q * 8 + 0] = bf2f_lo(v.x); xx[q * 8 + 1] = bf2f_hi(v.x);
            xx[q * 8 + 2] = bf2f_lo(v.y); xx[q * 8 + 3] = bf2f_hi(v.y);
            xx[q * 8 + 4] = bf2f_lo(v.z); xx[q * 8 + 5] = bf2f_hi(v.z);
            xx[q * 8 + 6] = bf2f_lo(v.w); xx[q * 8 + 7] = bf2f_hi(v.w);
        }
#pragma unroll
        for (int o = 0; o < 3; ++o)
#pragma unroll
            for (int ci = 0; ci < 32; ++ci)
                acc[o] += xx[ci] * wgt[o * 288 + ci * 9 + tap];
    }
    float4 s4; s4.x = acc[0]; s4.y = acc[1]; s4.z = acc[2]; s4.w = 0.f;
    *(float4*)(comb + ((long)b * HWPX + p) * 8 + 4) = s4;
}

// ---------------------------------------------------------------------------
// K5: 3->32 conv (img fp32 NCHW -> act NHWC bf16), gelu. 2 px/thread.
// ---------------------------------------------------------------------------
__global__ __launch_bounds__(256) void conv_in3_kernel(
    const float* __restrict__ img, const float* __restrict__ wgt,
    const float* __restrict__ bias, ushort* __restrict__ out)
{
    const int tid = threadIdx.x;
    const int p0 = (blockIdx.x * 256 + tid) * 2;
    const int b = blockIdx.y;
    const int hh = p0 / WID, ww = p0 - hh * WID;

    float acc[32][2];
#pragma unroll
    for (int o = 0; o < 32; ++o) { float bv = bias[o]; acc[o][0] = bv; acc[o][1] = bv; }

    const bool wlo = (ww > 0), whi = (ww + 2 < WID);
#pragma unroll
    for (int ci = 0; ci < 3; ++ci) {
        const float* ip = img + (long)(b * 3 + ci) * HWPX;
        float x[3][4];
#pragma unroll
        for (int dh = 0; dh < 3; ++dh) {
            const int hs = hh + dh - 1;
            const bool hok = (hs >= 0) && (hs < HGT);
            const float* rp_ = ip + hs * WID + ww;
            x[dh][0] = (hok && wlo) ? rp_[-1] : 0.f;
            x[dh][1] = hok ? rp_[0] : 0.f;
            x[dh][2] = hok ? rp_[1] : 0.f;
            x[dh][3] = (hok && whi) ? rp_[2] : 0.f;
        }
#pragma unroll
        for (int o = 0; o < 32; ++o) {
            const float* wv = wgt + o * 27 + ci * 9;   // uniform -> s_load
#pragma unroll
            for (int dh = 0; dh < 3; ++dh)
#pragma unroll
                for (int dw = 0; dw < 3; ++dw) {
                    const float w = wv[dh * 3 + dw];
                    acc[o][0] += x[dh][dw]     * w;
                    acc[o][1] += x[dh][dw + 1] * w;
                }
        }
    }

    ushort* op = out + ((long)b * HWPX + p0) * 32;
#pragma unroll
    for (int px = 0; px < 2; ++px) {
        uint u[16];
#pragma unroll
        for (int o2 = 0; o2 < 16; ++o2)
            u[o2] = pack2bf(gelu_f(acc[2 * o2][px]), gelu_f(acc[2 * o2 + 1][px]));
        uint4* dst = (uint4*)(op + px * 32);
#pragma unroll
        for (int q = 0; q < 4; ++q)
            dst[q] = make_uint4(u[4 * q], u[4 * q + 1], u[4 * q + 2], u[4 * q + 3]);
    }
}

// ---------------------------------------------------------------------------
// K6: MFMA 32->32 conv, staged LDS halo (r5/r7 structure, measured-best)
// + XCD-chunked bijective block swizzle (1152 = 8 XCD x 144; consecutive
// t share halo rows -> L2 locality within an XCD).
// Tile 8 rows x 64 px, 8 waves. Halo 10x66, CSTR=40 pad. 71.3 KB -> 2 blk/CU.
// ---------------------------------------------------------------------------
#define TH2 8
#define TW2 64
#define NTX (WID / TW2)          // 6
#define NTY (HGT / TH2)          // 48
#define NBLK (NTX * NTY * BB)    // 1152
#define CHUNK (NBLK / 8)         // 144
#define HALO_H2 10
#define HALO_W2 66
#define CSTR 40   // padded ushort stride per pixel (80 B)

template <bool HAS_RES>
__global__ __launch_bounds__(512, 4) void conv32_mfma(
    const ushort* __restrict__ in, const ushort* __restrict__ res,
    const float* __restrict__ wgt, const float* __restrict__ bias,
    const float* __restrict__ bn_g, const float* __restrict__ bn_bt,
    ushort* __restrict__ out)
{
    __shared__ ushort halo[HALO_H2 * HALO_W2 * CSTR];   // 52800 B
    __shared__ ushort wlA[9 * 2 * 64 * 8];              // 18432 B, lane-linear
    __shared__ float s_scale[32], s_shift[32];

    const int tid = threadIdx.x;
    // XCD-chunked bijective swizzle
    const int bid = blockIdx.x;
    const int t   = (bid & 7) * CHUNK + (bid >> 3);
    const int tx  = t % NTX;
    const int rem = t / NTX;
    const int ty  = rem % NTY;
    const int b   = rem / NTY;
    const int h0 = ty * TH2;
    const int w0 = tx * TW2;

    // pack A-frags: wlA[((tap*2+half)*64 + lane)*8 + j]
    for (int i = tid; i < 9 * 2 * 64 * 8; i += 512) {
        const int j    = i & 7;
        const int lane_= (i >> 3) & 63;
        const int half = (i >> 9) & 1;
        const int tap  = i >> 10;
        const int co = half * 16 + (lane_ & 15);
        const int ci = (lane_ >> 4) * 8 + j;
        wlA[i] = f2bf(wgt[co * 288 + ci * 9 + tap]);
    }
    if (tid < 32) {
        float sg = bn_g[tid] * 0.9999950000375f;   // g*(1+1e-5)^-0.5
        s_scale[tid] = sg;
        s_shift[tid] = bias[tid] * sg + bn_bt[tid];
    }

    // stage halo (zero-filled OOB); 16B chunks, coalesced NHWC reads
    const ushort* inb = in + (long)b * HWPX * 32;
    for (int i = tid; i < HALO_H2 * HALO_W2 * 4; i += 512) {
        const int row = i / (HALO_W2 * 4);
        const int rem2 = i - row * (HALO_W2 * 4);
        const int px = rem2 >> 2, q = rem2 & 3;
        const int gh = h0 + row - 1, gw = w0 + px - 1;
        uint4 v = make_uint4(0u, 0u, 0u, 0u);
        if (gh >= 0 && gh < HGT && gw >= 0 && gw < WID)
            v = *(const uint4*)(inb + ((long)gh * WID + gw) * 32 + q * 8);
        *(uint4*)(&halo[(row * HALO_W2 + px) * CSTR + q * 8]) = v;
    }
    __syncthreads();

    const int lane = tid & 63, wid = tid >> 6;
    const int l15 = lane & 15, kg = lane >> 4;
    const int r = wid;                      // one output row per wave

    f32x4 acc[4][2];
#pragma unroll
    for (int f = 0; f < 4; ++f)
#pragma unroll
        for (int cf = 0; cf < 2; ++cf)
            acc[f][cf] = (f32x4){0.f, 0.f, 0.f, 0.f};

#pragma unroll
    for (int tap = 0; tap < 9; ++tap) {
        const int dh = tap / 3, dw = tap - dh * 3;
        const bf16x8 a0 = *(const bf16x8*)(&wlA[((tap * 2 + 0) * 64 + lane) * 8]);
        const bf16x8 a1 = *(const bf16x8*)(&wlA[((tap * 2 + 1) * 64 + lane) * 8]);
#pragma unroll
        for (int f = 0; f < 4; ++f) {
            const int c0 = f * 16;
            const bf16x8 bfv = *(const bf16x8*)(
                &halo[((r + dh) * HALO_W2 + (c0 + dw + l15)) * CSTR + kg * 8]);
            acc[f][0] = __builtin_amdgcn_mfma_f32_16x16x32_bf16(a0, bfv, acc[f][0], 0, 0, 0);
            acc[f][1] = __builtin_amdgcn_mfma_f32_16x16x32_bf16(a1, bfv, acc[f][1], 0, 0, 0);
        }
    }

    // epilogue: scale/shift (+res) + gelu -> bf16 NHWC
#pragma unroll
    for (int f = 0; f < 4; ++f) {
        const int c0 = f * 16;
        const long gpx = (long)b * HWPX + (long)(h0 + r) * WID + (w0 + c0 + l15);
#pragma unroll
        for (int cf = 0; cf < 2; ++cf) {
            const int co0 = cf * 16 + kg * 4;
            const float4 sc = *(const float4*)(&s_scale[co0]);
            const float4 sh = *(const float4*)(&s_shift[co0]);
            float v0 = acc[f][cf][0] * sc.x + sh.x;
            float v1 = acc[f][cf][1] * sc.y + sh.y;
            float v2 = acc[f][cf][2] * sc.z + sh.z;
            float v3 = acc[f][cf][3] * sc.w + sh.w;
            if (HAS_RES) {
                const uint2 rv = *(const uint2*)(res + gpx * 32 + co0);
                v0 += bf2f_lo(rv.x); v1 += bf2f_hi(rv.x);
                v2 += bf2f_lo(rv.y); v3 += bf2f_hi(rv.y);
            }
            uint2 o;
            o.x = pack2bf(gelu_f(v0), gelu_f(v1));
            o.y = pack2bf(gelu_f(v2), gelu_f(v3));
            *(uint2*)(out + gpx * 32 + co0) = o;
        }
    }
}

// ---------------------------------------------------------------------------
// K8: 6->32 conv (comb fp32 [px][8] -> act NHWC bf16), gelu. 1 px/thread.
// ---------------------------------------------------------------------------
__global__ __launch_bounds__(256) void conv_in6_kernel(
    const float* __restrict__ comb, const float* __restrict__ wgt,
    const float* __restrict__ bias, ushort* __restrict__ out)
{
    const int p = blockIdx.x * 256 + threadIdx.x;
    const int b = blockIdx.y;
    const int hh = p / WID, ww = p - hh * WID;

    float acc[32];
#pragma unroll
    for (int o = 0; o < 32; ++o) acc[o] = bias[o];

#pragma unroll
    for (int tap = 0; tap < 9; ++tap) {
        const int dh = tap / 3, dw = tap - dh * 3;
        const int gh = hh + dh - 1, gw = ww + dw - 1;
        if (gh < 0 || gh >= HGT || gw < 0 || gw >= WID) continue;
        const float4* cp = (const float4*)(comb + ((long)b * HWPX + gh * WID + gw) * 8);
        const float4 qa = cp[0], qb = cp[1];
        const float xs[6] = {qa.x, qa.y, qa.z, qb.x, qb.y, qb.z};
#pragma unroll
        for (int o = 0; o < 32; ++o) {
            const float* wv = wgt + o * 54 + tap;   // uniform -> s_load
            acc[o] += xs[0] * wv[0]  + xs[1] * wv[9]  + xs[2] * wv[18]
                    + xs[3] * wv[27] + xs[4] * wv[36] + xs[5] * wv[45];
        }
    }

    ushort* op = out + ((long)b * HWPX + p) * 32;
    uint u[16];
#pragma unroll
    for (int o2 = 0; o2 < 16; ++o2)
        u[o2] = pack2bf(gelu_f(acc[2 * o2]), gelu_f(acc[2 * o2 + 1]));
    uint4* dst = (uint4*)op;
#pragma unroll
    for (int q = 0; q < 4; ++q)
        dst[q] = make_uint4(u[4 * q], u[4 * q + 1], u[4 * q + 2], u[4 * q + 3]);
}

// ---------------------------------------------------------------------------
// K9: final 32->3 conv (NHWC bf16) + img -> d_out fp32 NCHW. 1 px/thread.
// ---------------------------------------------------------------------------
__global__ __launch_bounds__(256) void conv_final_kernel(
    const ushort* __restrict__ in, const float* __restrict__ wgt,
    const float* __restrict__ bias, const float* __restrict__ img,
    float* __restrict__ outp)
{
    const int p = blockIdx.x * 256 + threadIdx.x;
    const int b = blockIdx.y;
    const int hh = p / WID, ww = p - hh * WID;
    float acc[3] = {bias[0], bias[1], bias[2]};

#pragma unroll
    for (int tap = 0; tap < 9; ++tap) {
        const int dh = tap / 3, dw = tap - dh * 3;
        const int gh = hh + dh - 1, gw = ww + dw - 1;
        if (gh < 0 || gh >= HGT || gw < 0 || gw >= WID) continue;
        const uint4* xp = (const uint4*)(in + ((long)b * HWPX + gh * WID + gw) * 32);
        float xx[32];
#pragma unroll
        for (int q = 0; q < 4; ++q) {
            uint4 v = xp[q];
            xx[q * 8 + 0] = bf2f_lo(v.x); xx[q * 8 + 1] = bf2f_hi(v.x);
            xx[q * 8 + 2] = bf2f_lo(v.y); xx[q * 8 + 3] = bf2f_hi(v.y);
            xx[q * 8 + 4] = bf2f_lo(v.z); xx[q * 8 + 5] = bf2f_hi(v.z);
            xx[q * 8 + 6] = bf2f_lo(v.w); xx[q * 8 + 7] = bf2f_hi(v.w);
        }
#pragma unroll
        for (int o = 0; o < 3; ++o)
#pragma unroll
            for (int ci = 0; ci < 32; ++ci)
                acc[o] += xx[ci] * wgt[o * 288 + ci * 9 + tap];
    }
#pragma unroll
    for (int o = 0; o < 3; ++o)
        outp[(long)(b * 3 + o) * HWPX + p] = acc[o] + img[(long)(b * 3 + o) * HWPX + p];
}

// ---------------------------------------------------------------------------
extern "C" void kernel_launch(void* const* d_in, const int* in_sizes, int n_in,
                              void* d_out, int out_size, void* d_ws, size_t ws_size,
                              hipStream_t stream)
{
    const int*   tokens  = (const int*)d_in[0];
    const float* img     = (const float*)d_in[1];
    const float* recon   = (const float*)d_in[2];
    const float* emb     = (const float*)d_in[3];
    const float* agg_w1  = (const float*)d_in[4];
    const float* agg_b1  = (const float*)d_in[5];
    const float* agg_w2  = (const float*)d_in[6];
    const float* agg_b2  = (const float*)d_in[7];
    const float* lut_w1  = (const float*)d_in[8];
    const float* lut_b1  = (const float*)d_in[9];
    const float* lut_w2  = (const float*)d_in[10];
    const float* lut_b2  = (const float*)d_in[11];
    const float* wg_w1   = (const float*)d_in[12];
    const float* wg_b1   = (const float*)d_in[13];
    const float* wg_w2   = (const float*)d_in[14];
    const float* wg_b2   = (const float*)d_in[15];
    const float* rp_cin_w = (const float*)d_in[16];
    const float* rp_cin_b = (const float*)d_in[17];
    const float* rp_rbA_w = (const float*)d_in[18];
    const float* rp_rbA_b = (const float*)d_in[19];
    const float* rp_rbA_g = (const float*)d_in[20];
    const float* rp_rbA_bt= (const float*)d_in[21];
    const float* rp_rbB_w = (const float*)d_in[22];
    const float* rp_rbB_b = (const float*)d_in[23];
    const float* rp_rbB_g = (const float*)d_in[24];
    const float* rp_rbB_bt= (const float*)d_in[25];
    const float* rp_cout_w= (const float*)d_in[26];
    const float* rp_cout_b= (const float*)d_in[27];
    const float* fu_cin_w = (const float*)d_in[28];
    const float* fu_cin_b = (const float*)d_in[29];
    const float* fu_rbA_w = (const float*)d_in[30];
    const float* fu_rbA_b = (const float*)d_in[31];
    const float* fu_rbA_g = (const float*)d_in[32];
    const float* fu_rbA_bt= (const float*)d_in[33];
    const float* fu_rbB_w = (const float*)d_in[34];
    const float* fu_rbB_b = (const float*)d_in[35];
    const float* fu_rbB_g = (const float*)d_in[36];
    const float* fu_rbB_bt= (const float*)d_in[37];
    const float* fu_cout_w= (const float*)d_in[38];
    const float* fu_cout_b= (const float*)d_in[39];

    float* ws = (float*)d_ws;
    float*  h3      = ws;                       // 1024
    float*  lwv     = ws + 1024;                // 32
    float*  partial = ws + 2048;                // 65536
    float*  clut    = ws + 69632;               // 431244
    float*  comb    = ws + 524288;              // 4718592  ([px][8] fp32)
    ushort* act0    = (ushort*)(ws + 5242880);  // 18874368 ushorts
    ushort* act1    = (ushort*)(ws + 14680064);
    ushort* act2    = (ushort*)(ws + 24117248);
    float*  outp    = (float*)d_out;

    // token head
    emb_partial_kernel<<<dim3(64, BB), dim3(256), 0, stream>>>(tokens, emb, partial);
    mlp_head_kernel<<<dim3(BB), dim3(1024), 0, stream>>>(
        partial, agg_w1, agg_b1, agg_w2, agg_b2,
        lut_w1, lut_b1, wg_w1, wg_b1, wg_w2, wg_b2, h3, lwv);

    // fused LUT GEMM + combine -> clut
    lut_fused_kernel<<<dim3((3 * G3 + 255) / 256), dim3(256), 0, stream>>>(
        h3, lwv, lut_w2, lut_b2, clut);

    const dim3 g1(HWPX / 256, BB), g2(HWPX / 512, BB), blk(256);
    const dim3 gm(NBLK), bm(512);

    // proc branch: img -> act0 -> act1 -> act2
    conv_in3_kernel<<<g2, blk, 0, stream>>>(img, rp_cin_w, rp_cin_b, act0);
    conv32_mfma<false><<<gm, bm, 0, stream>>>(
        act0, nullptr, rp_rbA_w, rp_rbA_b, rp_rbA_g, rp_rbA_bt, act1);
    conv32_mfma<true><<<gm, bm, 0, stream>>>(
        act1, act0, rp_rbB_w, rp_rbB_b, rp_rbB_g, rp_rbB_bt, act2);

    // merged: LUT apply + proc 32->3 -> comb
    applylut_out3_kernel<<<g1, blk, 0, stream>>>(
        clut, recon, act2, rp_cout_w, rp_cout_b, comb);

    // fuse branch: comb -> act0 -> act1 -> act2 -> d_out (+img)
    conv_in6_kernel<<<g1, blk, 0, stream>>>(comb, fu_cin_w, fu_cin_b, act0);
    conv32_mfma<false><<<gm, bm, 0, stream>>>(
        act0, nullptr, fu_rbA_w, fu_rbA_b, fu_rbA_g, fu_rbA_bt, act1);
    conv32_mfma<true><<<gm, bm, 0, stream>>>(
        act1, act0, fu_rbB_w, fu_rbB_b, fu_rbB_g, fu_rbB_bt, act2);
    conv_final_kernel<<<g1, blk, 0, stream>>>(act2, fu_cout_w, fu_cout_b, img, outp);
}

// Round 14
// 553.777 us; speedup vs baseline: 2.4479x; 1.0191x over previous
//
#include <hip/hip_runtime.h>
#include <hip/hip_bf16.h>
#include <math.h>

// Problem constants
#define BB    4
#define TT    1024
#define EE    256
#define HIDD  256
#define LLUT  8
#define HGT   384
#define WID   384
#define HWPX  147456      // 384*384
#define GSZ   33
#define G3    35937       // 33^3
#define NCOL  862488      // L*3*G3

typedef __attribute__((ext_vector_type(8))) short bf16x8;   // 8 bf16 = 4 VGPRs
typedef __attribute__((ext_vector_type(4))) float f32x4;

// fast gelu (tanh form): max abs dev from exact erf-gelu ~1e-3, threshold 2e-2
__device__ __forceinline__ float gelu_f(float x) {
    float s = 1.5957691216057308f * x * (1.0f + 0.044715f * x * x);
    float e = __expf(s);
    return x - x / (e + 1.0f);   // x*sigmoid(s); safe at +-inf
}

__device__ __forceinline__ ushort f2bf(float x) {
    uint u = __float_as_uint(x);
    return (ushort)((u + 0x7FFFu + ((u >> 16) & 1u)) >> 16);   // RNE
}
__device__ __forceinline__ uint pack2bf(float a, float b) {
    return (uint)f2bf(a) | ((uint)f2bf(b) << 16);
}
__device__ __forceinline__ float bf2f_lo(uint u) { return __uint_as_float(u << 16); }
__device__ __forceinline__ float bf2f_hi(uint u) { return __uint_as_float(u & 0xFFFF0000u); }

// ---------------------------------------------------------------------------
// K-1: pack conv32 A-fragments for all 4 layers, lane-linear bf16.
// wpk[layer][(tap*2+half)*512 + lane*8 + j] = bf16(W[half*16+(lane&15)]
//                                                  [(lane>>4)*8+j][tap])
// 18.4 KB per layer -> L1-resident on each CU during conv32.
// ---------------------------------------------------------------------------
__global__ __launch_bounds__(256) void pack_wconv_kernel(
    const float* __restrict__ w0, const float* __restrict__ w1,
    const float* __restrict__ w2, const float* __restrict__ w3,
    ushort* __restrict__ wpk)
{
    const int layer = blockIdx.x;
    const float* w = (layer == 0) ? w0 : (layer == 1) ? w1 : (layer == 2) ? w2 : w3;
    ushort* dst = wpk + layer * 9216;
    for (int i = threadIdx.x; i < 9216; i += 256) {
        const int j    = i & 7;
        const int lane = (i >> 3) & 63;
        const int half = (i >> 9) & 1;
        const int tap  = i >> 10;
        const int co = half * 16 + (lane & 15);
        const int ci = (lane >> 4) * 8 + j;
        dst[i] = f2bf(w[co * 288 + ci * 9 + tap]);
    }
}

// ---------------------------------------------------------------------------
// K0: embedding-mean partial sums. grid (64, B).
// ---------------------------------------------------------------------------
__global__ __launch_bounds__(256) void emb_partial_kernel(
    const int* __restrict__ tokens, const float* __restrict__ emb,
    float* __restrict__ partial)
{
    const int s = blockIdx.x, b = blockIdx.y, tid = threadIdx.x;
    const int* tok = tokens + b * TT + s * 16;
    float acc = 0.f;
#pragma unroll
    for (int t = 0; t < 16; ++t) acc += emb[tok[t] * EE + tid];
    partial[(b * 64 + s) * EE + tid] = acc;
}

// ---------------------------------------------------------------------------
// K1: fused token head, latency-parallel (r7 version, measured-good).
// ---------------------------------------------------------------------------
__global__ __launch_bounds__(1024) void mlp_head_kernel(
    const float* __restrict__ partial,
    const float* __restrict__ aw1, const float* __restrict__ ab1,
    const float* __restrict__ aw2, const float* __restrict__ ab2,
    const float* __restrict__ lw1, const float* __restrict__ lb1,
    const float* __restrict__ gw1, const float* __restrict__ gb1,
    const float* __restrict__ gw2, const float* __restrict__ gb2,
    float* __restrict__ h3_out, float* __restrict__ lw_out)
{
    const int b = blockIdx.x;
    const int tid = threadIdx.x;
    const int o = tid & 255;
    const int q = tid >> 8;
    __shared__ float tf[256], h1[256], tf2s[256], h4[64], lg[8];
    __shared__ float red[4][256];

    {
        float acc = 0.f;
#pragma unroll
        for (int s = 0; s < 16; ++s)
            acc += partial[(b * 64 + q * 16 + s) * EE + o];
        red[q][o] = acc;
    }
    __syncthreads();
    if (tid < 256)
        tf[tid] = (red[0][tid] + red[1][tid] + red[2][tid] + red[3][tid]) * (1.0f / TT);
    __syncthreads();

    {
        float s = 0.f;
#pragma unroll 8
        for (int j = 0; j < 64; ++j) {
            const int k = (q << 6) + j;
            s += tf[k] * aw1[k * HIDD + o];
        }
        red[q][o] = s;
    }
    __syncthreads();
    if (tid < 256)
        h1[tid] = gelu_f(red[0][tid] + red[1][tid] + red[2][tid] + red[3][tid] + ab1[tid]);
    __syncthreads();

    {
        float s = 0.f;
#pragma unroll 8
        for (int j = 0; j < 64; ++j) {
            const int k = (q << 6) + j;
            s += h1[k] * aw2[k * HIDD + o];
        }
        red[q][o] = s;
    }
    __syncthreads();
    if (tid < 256)
        tf2s[tid] = red[0][tid] + red[1][tid] + red[2][tid] + red[3][tid] + ab2[tid];
    __syncthreads();

    {
        float s = 0.f;
#pragma unroll 8
        for (int j = 0; j < 64; ++j) {
            const int k = (q << 6) + j;
            s += tf2s[k] * lw1[k * HIDD + o];
        }
        red[q][o] = s;
    }
    __syncthreads();
    if (tid < 256)
        h3_out[b * HIDD + tid] =
            gelu_f(red[0][tid] + red[1][tid] + red[2][tid] + red[3][tid] + lb1[tid]);
    __syncthreads();

    {
        const int o64 = tid & 63, q16 = tid >> 6;
        float s = 0.f;
#pragma unroll
        for (int j = 0; j < 16; ++j) {
            const int k = q16 * 16 + j;
            s += tf2s[k] * gw1[k * 64 + o64];
        }
        ((float*)red)[q16 * 64 + o64] = s;
    }
    __syncthreads();
    if (tid < 64) {
        float s = gb1[tid];
#pragma unroll
        for (int r = 0; r < 16; ++r) s += ((float*)red)[r * 64 + tid];
        h4[tid] = gelu_f(s);
    }
    __syncthreads();

    if (tid < 8) {
        float s = gb2[tid];
#pragma unroll 8
        for (int k = 0; k < 64; ++k) s += h4[k] * gw2[k * LLUT + tid];
        lg[tid] = s;
    }
    __syncthreads();
    if (tid == 0) {
        float m = lg[0];
        for (int i = 1; i < LLUT; ++i) m = fmaxf(m, lg[i]);
        float ssum = 0.f, ex[LLUT];
        for (int i = 0; i < LLUT; ++i) { ex[i] = expf(lg[i] - m); ssum += ex[i]; }
        for (int i = 0; i < LLUT; ++i) lw_out[b * LLUT + i] = ex[i] / ssum;
    }
}

// ---------------------------------------------------------------------------
// K2: fused LUT-GEMM + softmax-combine -> clut (883 MB w2 stream, ~140 us).
// ---------------------------------------------------------------------------
__global__ __launch_bounds__(256) void lut_fused_kernel(
    const float* __restrict__ h3, const float* __restrict__ lwv,
    const float* __restrict__ w2, const float* __restrict__ b2,
    float* __restrict__ clut)
{
    __shared__ float h[BB * HIDD];
    __shared__ float lws[BB * LLUT];
    const int tid = threadIdx.x;
    for (int i = tid; i < BB * HIDD; i += 256) h[i] = h3[i];
    if (tid < BB * LLUT) lws[tid] = lwv[tid];
    __syncthreads();

    const int idx = blockIdx.x * 256 + tid;
    if (idx >= 3 * G3) return;
    const int c = idx / G3, v = idx - c * G3;

    float acc[BB][LLUT];
#pragma unroll
    for (int b = 0; b < BB; ++b)
#pragma unroll
        for (int l = 0; l < LLUT; ++l) acc[b][l] = 0.f;

    const float* wbase = w2 + (long)c * G3 + v;   // + l*3*G3 + k*NCOL
#pragma unroll 4
    for (int k = 0; k < HIDD; ++k) {
        const float* row = wbase + (long)k * NCOL;
        float wl[LLUT];
#pragma unroll
        for (int l = 0; l < LLUT; ++l) wl[l] = row[l * 3 * G3];
#pragma unroll
        for (int b = 0; b < BB; ++b) {
            const float hb = h[b * HIDD + k];
#pragma unroll
            for (int l = 0; l < LLUT; ++l) acc[b][l] += wl[l] * hb;
        }
    }

    float bb[LLUT];
#pragma unroll
    for (int l = 0; l < LLUT; ++l) bb[l] = b2[(long)(l * 3 + c) * G3 + v];

#pragma unroll
    for (int b = 0; b < BB; ++b) {
        float s = 0.f;
#pragma unroll
        for (int l = 0; l < LLUT; ++l) s += lws[b * LLUT + l] * (acc[b][l] + bb[l]);
        clut[(long)(b * 3 + c) * G3 + v] = s;
    }
}

// ---------------------------------------------------------------------------
// K4+K7 merged: trilinear LUT apply (comb bf16 slots 0..2) + 32->3 proc conv
// from act2 (slots 4..6) -> comb [px][8] BF16 (16 B/px, halves traffic).
// ---------------------------------------------------------------------------
__global__ __launch_bounds__(256) void applylut_out3_kernel(
    const float* __restrict__ clut, const float* __restrict__ recon,
    const ushort* __restrict__ act2, const float* __restrict__ wgt,
    const float* __restrict__ bias, ushort* __restrict__ comb)
{
    const int p = blockIdx.x * 256 + threadIdx.x;
    const int b = blockIdx.y;

    // --- LUT part ---
    const float* rc = recon + (long)b * 3 * HWPX;
    float cr = fminf(fmaxf(rc[p] * 32.f, 0.f), 32.f);
    float cg = fminf(fmaxf(rc[HWPX + p] * 32.f, 0.f), 32.f);
    float cb = fminf(fmaxf(rc[2 * HWPX + p] * 32.f, 0.f), 32.f);
    float fr = fminf(floorf(cr), 31.f);
    float fg = fminf(floorf(cg), 31.f);
    float fb = fminf(floorf(cb), 31.f);
    float tr = cr - fr, tg = cg - fg, tb_ = cb - fb;
    int idx = (((int)fr * GSZ + (int)fg) * GSZ + (int)fb);
    float c[3];
#pragma unroll
    for (int ch = 0; ch < 3; ++ch) {
        const float* lut = clut + (long)(b * 3 + ch) * G3;
        float v000 = lut[idx],                  v001 = lut[idx + 1];
        float v010 = lut[idx + GSZ],            v011 = lut[idx + GSZ + 1];
        float v100 = lut[idx + GSZ * GSZ],      v101 = lut[idx + GSZ * GSZ + 1];
        float v110 = lut[idx + GSZ * GSZ + GSZ], v111 = lut[idx + GSZ * GSZ + GSZ + 1];
        float c00 = v000 + (v001 - v000) * tb_;
        float c01 = v010 + (v011 - v010) * tb_;
        float c10 = v100 + (v101 - v100) * tb_;
        float c11 = v110 + (v111 - v110) * tb_;
        float c0 = c00 + (c01 - c00) * tg;
        float c1 = c10 + (c11 - c10) * tg;
        c[ch] = c0 + (c1 - c0) * tr;
    }

    // --- proc 32->3 conv part ---
    const int hh = p / WID, ww = p - hh * WID;
    float acc[3] = {bias[0], bias[1], bias[2]};
#pragma unroll
    for (int tap = 0; tap < 9; ++tap) {
        const int dh = tap / 3, dw = tap - dh * 3;
        const int gh = hh + dh - 1, gw = ww + dw - 1;
        if (gh < 0 || gh >= HGT || gw < 0 || gw >= WID) continue;
        const uint4* xp = (const uint4*)(act2 + ((long)b * HWPX + gh * WID + gw) * 32);
        float xx[32];
#pragma unroll
        for (int q = 0; q < 4; ++q) {
            uint4 v = xp[q];
            xx[q * 8 + 0] = bf2f_lo(v.x); xx[q * 8 + 1] = bf2f_hi(v.x);
            xx[q * 8 + 2] = bf2f_lo(v.y); xx[q * 8 + 3] = bf2f_hi(v.y);
            xx[q * 8 + 4] = bf2f_lo(v.z); xx[q * 8 + 5] = bf2f_hi(v.z);
            xx[q * 8 + 6] = bf2f_lo(v.w); xx[q * 8 + 7] = bf2f_hi(v.w);
        }
#pragma unroll
        for (int o = 0; o < 3; ++o)
#pragma unroll
            for (int ci = 0; ci < 32; ++ci)
                acc[o] += xx[ci] * wgt[o * 288 + ci * 9 + tap];
    }

    // pack: x={l0,l1}, y={l2,-}, z={p0,p1}, w={p2,-}
    uint4 u;
    u.x = pack2bf(c[0], c[1]);
    u.y = pack2bf(c[2], 0.f);
    u.z = pack2bf(acc[0], acc[1]);
    u.w = pack2bf(acc[2], 0.f);
    *(uint4*)(comb + ((long)b * HWPX + p) * 8) = u;
}

// ---------------------------------------------------------------------------
// K5: 3->32 conv (img fp32 NCHW -> act NHWC bf16), gelu. 2 px/thread.
// ---------------------------------------------------------------------------
__global__ __launch_bounds__(256) void conv_in3_kernel(
    const float* __restrict__ img, const float* __restrict__ wgt,
    const float* __restrict__ bias, ushort* __restrict__ out)
{
    const int tid = threadIdx.x;
    const int p0 = (blockIdx.x * 256 + tid) * 2;
    const int b = blockIdx.y;
    const int hh = p0 / WID, ww = p0 - hh * WID;

    float acc[32][2];
#pragma unroll
    for (int o = 0; o < 32; ++o) { float bv = bias[o]; acc[o][0] = bv; acc[o][1] = bv; }

    const bool wlo = (ww > 0), whi = (ww + 2 < WID);
#pragma unroll
    for (int ci = 0; ci < 3; ++ci) {
        const float* ip = img + (long)(b * 3 + ci) * HWPX;
        float x[3][4];
#pragma unroll
        for (int dh = 0; dh < 3; ++dh) {
            const int hs = hh + dh - 1;
            const bool hok = (hs >= 0) && (hs < HGT);
            const float* rp_ = ip + hs * WID + ww;
            x[dh][0] = (hok && wlo) ? rp_[-1] : 0.f;
            x[dh][1] = hok ? rp_[0] : 0.f;
            x[dh][2] = hok ? rp_[1] : 0.f;
            x[dh][3] = (hok && whi) ? rp_[2] : 0.f;
        }
#pragma unroll
        for (int o = 0; o < 32; ++o) {
            const float* wv = wgt + o * 27 + ci * 9;   // uniform -> s_load
#pragma unroll
            for (int dh = 0; dh < 3; ++dh)
#pragma unroll
                for (int dw = 0; dw < 3; ++dw) {
                    const float w = wv[dh * 3 + dw];
                    acc[o][0] += x[dh][dw]     * w;
                    acc[o][1] += x[dh][dw + 1] * w;
                }
        }
    }

    ushort* op = out + ((long)b * HWPX + p0) * 32;
#pragma unroll
    for (int px = 0; px < 2; ++px) {
        uint u[16];
#pragma unroll
        for (int o2 = 0; o2 < 16; ++o2)
            u[o2] = pack2bf(gelu_f(acc[2 * o2][px]), gelu_f(acc[2 * o2 + 1][px]));
        uint4* dst = (uint4*)(op + px * 32);
#pragma unroll
        for (int q = 0; q < 4; ++q)
            dst[q] = make_uint4(u[4 * q], u[4 * q + 1], u[4 * q + 2], u[4 * q + 3]);
    }
}

// ---------------------------------------------------------------------------
// K6 v4: MFMA 32->32 conv. A-frags PRE-PACKED in global (lane-linear 1KB/wave
// loads, L1-resident 18.4 KB) -> no per-block pack, LDS = halo only (52.8 KB)
// -> 3 blocks/CU (was 2). XCD-chunked bijective swizzle kept.
// Tile 8 rows x 64 px, 8 waves. Halo 10x66, CSTR=40 (conflict-free b128).
// ---------------------------------------------------------------------------
#define TH2 8
#define TW2 64
#define NTX (WID / TW2)          // 6
#define NTY (HGT / TH2)          // 48
#define NBLK (NTX * NTY * BB)    // 1152
#define CHUNK (NBLK / 8)         // 144
#define HALO_H2 10
#define HALO_W2 66
#define CSTR 40   // padded ushort stride per pixel (80 B)

template <bool HAS_RES>
__global__ __launch_bounds__(512, 6) void conv32_mfma(
    const ushort* __restrict__ in, const ushort* __restrict__ res,
    const ushort* __restrict__ wpk, const float* __restrict__ bias,
    const float* __restrict__ bn_g, const float* __restrict__ bn_bt,
    ushort* __restrict__ out)
{
    __shared__ ushort halo[HALO_H2 * HALO_W2 * CSTR];   // 52800 B
    __shared__ float s_scale[32], s_shift[32];

    const int tid = threadIdx.x;
    // XCD-chunked bijective swizzle
    const int bid = blockIdx.x;
    const int t   = (bid & 7) * CHUNK + (bid >> 3);
    const int tx  = t % NTX;
    const int rem = t / NTX;
    const int ty  = rem % NTY;
    const int b   = rem / NTY;
    const int h0 = ty * TH2;
    const int w0 = tx * TW2;

    if (tid < 32) {
        float sg = bn_g[tid] * 0.9999950000375f;   // g*(1+1e-5)^-0.5
        s_scale[tid] = sg;
        s_shift[tid] = bias[tid] * sg + bn_bt[tid];
    }

    // stage halo (zero-filled OOB); 16B chunks, coalesced NHWC reads
    const ushort* inb = in + (long)b * HWPX * 32;
    for (int i = tid; i < HALO_H2 * HALO_W2 * 4; i += 512) {
        const int row = i / (HALO_W2 * 4);
        const int rem2 = i - row * (HALO_W2 * 4);
        const int px = rem2 >> 2, q = rem2 & 3;
        const int gh = h0 + row - 1, gw = w0 + px - 1;
        uint4 v = make_uint4(0u, 0u, 0u, 0u);
        if (gh >= 0 && gh < HGT && gw >= 0 && gw < WID)
            v = *(const uint4*)(inb + ((long)gh * WID + gw) * 32 + q * 8);
        *(uint4*)(&halo[(row * HALO_W2 + px) * CSTR + q * 8]) = v;
    }
    __syncthreads();

    const int lane = tid & 63, wid = tid >> 6;
    const int l15 = lane & 15, kg = lane >> 4;
    const int r = wid;                      // one output row per wave
    const ushort* wlane = wpk + lane * 8;   // lane-linear A base

    f32x4 acc[4][2];
#pragma unroll
    for (int f = 0; f < 4; ++f)
#pragma unroll
        for (int cf = 0; cf < 2; ++cf)
            acc[f][cf] = (f32x4){0.f, 0.f, 0.f, 0.f};

#pragma unroll
    for (int tap = 0; tap < 9; ++tap) {
        const int dh = tap / 3, dw = tap - dh * 3;
        const bf16x8 a0 = *(const bf16x8*)(wlane + (tap * 2 + 0) * 512);
        const bf16x8 a1 = *(const bf16x8*)(wlane + (tap * 2 + 1) * 512);
#pragma unroll
        for (int f = 0; f < 4; ++f) {
            const int c0 = f * 16;
            const bf16x8 bfv = *(const bf16x8*)(
                &halo[((r + dh) * HALO_W2 + (c0 + dw + l15)) * CSTR + kg * 8]);
            acc[f][0] = __builtin_amdgcn_mfma_f32_16x16x32_bf16(a0, bfv, acc[f][0], 0, 0, 0);
            acc[f][1] = __builtin_amdgcn_mfma_f32_16x16x32_bf16(a1, bfv, acc[f][1], 0, 0, 0);
        }
    }

    // epilogue: scale/shift (+res) + gelu -> bf16 NHWC
#pragma unroll
    for (int f = 0; f < 4; ++f) {
        const int c0 = f * 16;
        const long gpx = (long)b * HWPX + (long)(h0 + r) * WID + (w0 + c0 + l15);
#pragma unroll
        for (int cf = 0; cf < 2; ++cf) {
            const int co0 = cf * 16 + kg * 4;
            const float4 sc = *(const float4*)(&s_scale[co0]);
            const float4 sh = *(const float4*)(&s_shift[co0]);
            float v0 = acc[f][cf][0] * sc.x + sh.x;
            float v1 = acc[f][cf][1] * sc.y + sh.y;
            float v2 = acc[f][cf][2] * sc.z + sh.z;
            float v3 = acc[f][cf][3] * sc.w + sh.w;
            if (HAS_RES) {
                const uint2 rv = *(const uint2*)(res + gpx * 32 + co0);
                v0 += bf2f_lo(rv.x); v1 += bf2f_hi(rv.x);
                v2 += bf2f_lo(rv.y); v3 += bf2f_hi(rv.y);
            }
            uint2 o;
            o.x = pack2bf(gelu_f(v0), gelu_f(v1));
            o.y = pack2bf(gelu_f(v2), gelu_f(v3));
            *(uint2*)(out + gpx * 32 + co0) = o;
        }
    }
}

// ---------------------------------------------------------------------------
// K8: 6->32 conv (comb BF16 [px][8] -> act NHWC bf16), gelu. 1 px/thread.
// ---------------------------------------------------------------------------
__global__ __launch_bounds__(256) void conv_in6_kernel(
    const ushort* __restrict__ comb, const float* __restrict__ wgt,
    const float* __restrict__ bias, ushort* __restrict__ out)
{
    const int p = blockIdx.x * 256 + threadIdx.x;
    const int b = blockIdx.y;
    const int hh = p / WID, ww = p - hh * WID;

    float acc[32];
#pragma unroll
    for (int o = 0; o < 32; ++o) acc[o] = bias[o];

#pragma unroll
    for (int tap = 0; tap < 9; ++tap) {
        const int dh = tap / 3, dw = tap - dh * 3;
        const int gh = hh + dh - 1, gw = ww + dw - 1;
        if (gh < 0 || gh >= HGT || gw < 0 || gw >= WID) continue;
        const uint4 v = *(const uint4*)(comb + ((long)b * HWPX + gh * WID + gw) * 8);
        const float xs[6] = {bf2f_lo(v.x), bf2f_hi(v.x), bf2f_lo(v.y),
                             bf2f_lo(v.z), bf2f_hi(v.z), bf2f_lo(v.w)};
#pragma unroll
        for (int o = 0; o < 32; ++o) {
            const float* wv = wgt + o * 54 + tap;   // uniform -> s_load
            acc[o] += xs[0] * wv[0]  + xs[1] * wv[9]  + xs[2] * wv[18]
                    + xs[3] * wv[27] + xs[4] * wv[36] + xs[5] * wv[45];
        }
    }

    ushort* op = out + ((long)b * HWPX + p) * 32;
    uint u[16];
#pragma unroll
    for (int o2 = 0; o2 < 16; ++o2)
        u[o2] = pack2bf(gelu_f(acc[2 * o2]), gelu_f(acc[2 * o2 + 1]));
    uint4* dst = (uint4*)op;
#pragma unroll
    for (int q = 0; q < 4; ++q)
        dst[q] = make_uint4(u[4 * q], u[4 * q + 1], u[4 * q + 2], u[4 * q + 3]);
}

// ---------------------------------------------------------------------------
// K9: final 32->3 conv (NHWC bf16) + img -> d_out fp32 NCHW. 1 px/thread.
// ---------------------------------------------------------------------------
__global__ __launch_bounds__(256) void conv_final_kernel(
    const ushort* __restrict__ in, const float* __restrict__ wgt,
    const float* __restrict__ bias, const float* __restrict__ img,
    float* __restrict__ outp)
{
    const int p = blockIdx.x * 256 + threadIdx.x;
    const int b = blockIdx.y;
    const int hh = p / WID, ww = p - hh * WID;
    float acc[3] = {bias[0], bias[1], bias[2]};

#pragma unroll
    for (int tap = 0; tap < 9; ++tap) {
        const int dh = tap / 3, dw = tap - dh * 3;
        const int gh = hh + dh - 1, gw = ww + dw - 1;
        if (gh < 0 || gh >= HGT || gw < 0 || gw >= WID) continue;
        const uint4* xp = (const uint4*)(in + ((long)b * HWPX + gh * WID + gw) * 32);
        float xx[32];
#pragma unroll
        for (int q = 0; q < 4; ++q) {
            uint4 v = xp[q];
            xx[q * 8 + 0] = bf2f_lo(v.x); xx[q * 8 + 1] = bf2f_hi(v.x);
            xx[q * 8 + 2] = bf2f_lo(v.y); xx[q * 8 + 3] = bf2f_hi(v.y);
            xx[q * 8 + 4] = bf2f_lo(v.z); xx[q * 8 + 5] = bf2f_hi(v.z);
            xx[q * 8 + 6] = bf2f_lo(v.w); xx[q * 8 + 7] = bf2f_hi(v.w);
        }
#pragma unroll
        for (int o = 0; o < 3; ++o)
#pragma unroll
            for (int ci = 0; ci < 32; ++ci)
                acc[o] += xx[ci] * wgt[o * 288 + ci * 9 + tap];
    }
#pragma unroll
    for (int o = 0; o < 3; ++o)
        outp[(long)(b * 3 + o) * HWPX + p] = acc[o] + img[(long)(b * 3 + o) * HWPX + p];
}

// ---------------------------------------------------------------------------
extern "C" void kernel_launch(void* const* d_in, const int* in_sizes, int n_in,
                              void* d_out, int out_size, void* d_ws, size_t ws_size,
                              hipStream_t stream)
{
    const int*   tokens  = (const int*)d_in[0];
    const float* img     = (const float*)d_in[1];
    const float* recon   = (const float*)d_in[2];
    const float* emb     = (const float*)d_in[3];
    const float* agg_w1  = (const float*)d_in[4];
    const float* agg_b1  = (const float*)d_in[5];
    const float* agg_w2  = (const float*)d_in[6];
    const float* agg_b2  = (const float*)d_in[7];
    const float* lut_w1  = (const float*)d_in[8];
    const float* lut_b1  = (const float*)d_in[9];
    const float* lut_w2  = (const float*)d_in[10];
    const float* lut_b2  = (const float*)d_in[11];
    const float* wg_w1   = (const float*)d_in[12];
    const float* wg_b1   = (const float*)d_in[13];
    const float* wg_w2   = (const float*)d_in[14];
    const float* wg_b2   = (const float*)d_in[15];
    const float* rp_cin_w = (const float*)d_in[16];
    const float* rp_cin_b = (const float*)d_in[17];
    const float* rp_rbA_w = (const float*)d_in[18];
    const float* rp_rbA_b = (const float*)d_in[19];
    const float* rp_rbA_g = (const float*)d_in[20];
    const float* rp_rbA_bt= (const float*)d_in[21];
    const float* rp_rbB_w = (const float*)d_in[22];
    const float* rp_rbB_b = (const float*)d_in[23];
    const float* rp_rbB_g = (const float*)d_in[24];
    const float* rp_rbB_bt= (const float*)d_in[25];
    const float* rp_cout_w= (const float*)d_in[26];
    const float* rp_cout_b= (const float*)d_in[27];
    const float* fu_cin_w = (const float*)d_in[28];
    const float* fu_cin_b = (const float*)d_in[29];
    const float* fu_rbA_w = (const float*)d_in[30];
    const float* fu_rbA_b = (const float*)d_in[31];
    const float* fu_rbA_g = (const float*)d_in[32];
    const float* fu_rbA_bt= (const float*)d_in[33];
    const float* fu_rbB_w = (const float*)d_in[34];
    const float* fu_rbB_b = (const float*)d_in[35];
    const float* fu_rbB_g = (const float*)d_in[36];
    const float* fu_rbB_bt= (const float*)d_in[37];
    const float* fu_cout_w= (const float*)d_in[38];
    const float* fu_cout_b= (const float*)d_in[39];

    float* ws = (float*)d_ws;
    float*  h3      = ws;                       // 1024
    float*  lwv     = ws + 1024;                // 32
    float*  partial = ws + 2048;                // 65536
    float*  clut    = ws + 69632;               // 431244
    ushort* wpack   = (ushort*)(ws + 524288);   // 4*9216 ushorts
    ushort* comb    = (ushort*)(ws + 589824);   // 4*HWPX*8 ushorts (bf16)
    ushort* act0    = (ushort*)(ws + 3145728);  // 18874368 ushorts
    ushort* act1    = (ushort*)(ws + 12582912);
    ushort* act2    = (ushort*)(ws + 22020096);
    float*  outp    = (float*)d_out;

    // pack conv32 A-fragments once (layers: rpA, rpB, fuA, fuB)
    pack_wconv_kernel<<<dim3(4), dim3(256), 0, stream>>>(
        rp_rbA_w, rp_rbB_w, fu_rbA_w, fu_rbB_w, wpack);

    // token head
    emb_partial_kernel<<<dim3(64, BB), dim3(256), 0, stream>>>(tokens, emb, partial);
    mlp_head_kernel<<<dim3(BB), dim3(1024), 0, stream>>>(
        partial, agg_w1, agg_b1, agg_w2, agg_b2,
        lut_w1, lut_b1, wg_w1, wg_b1, wg_w2, wg_b2, h3, lwv);

    // fused LUT GEMM + combine -> clut
    lut_fused_kernel<<<dim3((3 * G3 + 255) / 256), dim3(256), 0, stream>>>(
        h3, lwv, lut_w2, lut_b2, clut);

    const dim3 g1(HWPX / 256, BB), g2(HWPX / 512, BB), blk(256);
    const dim3 gm(NBLK), bm(512);

    // proc branch: img -> act0 -> act1 -> act2
    conv_in3_kernel<<<g2, blk, 0, stream>>>(img, rp_cin_w, rp_cin_b, act0);
    conv32_mfma<false><<<gm, bm, 0, stream>>>(
        act0, nullptr, wpack + 0 * 9216, rp_rbA_b, rp_rbA_g, rp_rbA_bt, act1);
    conv32_mfma<true><<<gm, bm, 0, stream>>>(
        act1, act0, wpack + 1 * 9216, rp_rbB_b, rp_rbB_g, rp_rbB_bt, act2);

    // merged: LUT apply + proc 32->3 -> comb (bf16)
    applylut_out3_kernel<<<g1, blk, 0, stream>>>(
        clut, recon, act2, rp_cout_w, rp_cout_b, comb);

    // fuse branch: comb -> act0 -> act1 -> act2 -> d_out (+img)
    conv_in6_kernel<<<g1, blk, 0, stream>>>(comb, fu_cin_w, fu_cin_b, act0);
    conv32_mfma<false><<<gm, bm, 0, stream>>>(
        act0, nullptr, wpack + 2 * 9216, fu_rbA_b, fu_rbA_g, fu_rbA_bt, act1);
    conv32_mfma<true><<<gm, bm, 0, stream>>>(
        act1, act0, wpack + 3 * 9216, fu_rbB_b, fu_rbB_g, fu_rbB_bt, act2);
    conv_final_kernel<<<g1, blk, 0, stream>>>(act2, fu_cout_w, fu_cout_b, img, outp);
}